// Round 1
// 123.854 us; speedup vs baseline: 1.0103x; 1.0103x over previous
//
#include <hip/hip_runtime.h>

#define T_STEPS 345
#define B_SZ    128
#define IN_SZ   13
#define H_SZ    128
#define OUT_SZ  9
#define XPITCH  16
#define TPAD    384                 // padded t-extent (384 = 6*64)
#define CPAD    388                 // cur2 LDS row pitch (floats); 388*4=1552B, 16B-aligned
#define NBO     (B_SZ * OUT_SZ)    // 1152

// Fully fused SNN: layer-1 scan -> ballot masks (LDS) -> bit-masked cur2 GEMM (LDS)
// -> layer-2 scan -> out. Dependency is per-batch, so one workgroup handles one
// batch end-to-end with __syncthreads() between phases (no grid sync).
// Two blocks per batch: both run the (cheap, wall-clock-parallel) phase-1 scan,
// then split phase 2/3 by output row: half 0 -> o in [0,5), half 1 -> o in [5,9).
// Phase-1 FMA chain / mem1 update is BIT-IDENTICAL to the verified 3-kernel
// version (knife-edge numerics — do not reorder).
__global__ __launch_bounds__(512, 2)
void snn_fused(const float* __restrict__ x, const float* __restrict__ W1,
               const float* __restrict__ b1, const float* __restrict__ W2,
               const float* __restrict__ b2,
               const float* __restrict__ beta1p, const float* __restrict__ thr1p,
               const float* __restrict__ beta2p, const float* __restrict__ thr2p,
               float* __restrict__ out)
{
    const int b    = blockIdx.x >> 1;
    const int half = blockIdx.x & 1;
    const int tid  = threadIdx.x;

    __shared__ float xst[(T_STEPS + 3) * XPITCH];      // 22,272 B (pad rows: clampless prefetch)
    __shared__ unsigned long long msh[TPAD * 2];       //  6,144 B  u64 [t][2] ballot masks
    __shared__ float c2s[OUT_SZ * CPAD];               // 13,968 B  cur2 rows

    // ---------------- phase 0: stage x[b] into LDS (all 512 threads) ----------------
    const float* xb = x + (size_t)b * (IN_SZ * T_STEPS);
    for (int i = tid; i < IN_SZ * T_STEPS; i += 512) {
        const int c = i / T_STEPS;
        const int t = i - c * T_STEPS;
        xst[t * XPITCH + c] = xb[i];
    }
    __syncthreads();

    // ---------------- phase 1: layer-1 scan, threads 0..127 == neuron h ----------------
    // Spikes exported as per-wave ballot masks into msh[t*2 + (tid>>6)].
    if (tid < 128) {
        const float bt1 = fminf(fmaxf(beta1p[0], 0.0f), 1.0f);
        const float th1 = thr1p[0];

        float w1r[IN_SZ];
#pragma unroll
        for (int c = 0; c < IN_SZ; ++c) w1r[c] = W1[tid * IN_SZ + c];
        const float b1r = b1[tid];

        float mem1 = 0.0f;
        unsigned long long* mp = msh + (tid >> 6);
        const bool store_lane = (tid & 63) == 0;

        const float4* xq = (const float4*)xst;
        // Two in-flight x-row register sets (steps t and t+1)
        float4 a0 = xq[0], a1 = xq[1], a2 = xq[2]; float a3 = xst[12];
        float4 c0 = xq[4], c1 = xq[5], c2 = xq[6]; float c3 = xst[XPITCH + 12];

        int t = 0;
        for (; t < T_STEPS - 1; t += 2) {
            const float xa[IN_SZ] = { a0.x,a0.y,a0.z,a0.w, a1.x,a1.y,a1.z,a1.w,
                                      a2.x,a2.y,a2.z,a2.w, a3 };
            const float xc[IN_SZ] = { c0.x,c0.y,c0.z,c0.w, c1.x,c1.y,c1.z,c1.w,
                                      c2.x,c2.y,c2.z,c2.w, c3 };
            // prefetch rows t+2, t+3 (pad rows cover the tail)
            a0 = xq[(t+2)*4+0]; a1 = xq[(t+2)*4+1]; a2 = xq[(t+2)*4+2]; a3 = xst[(t+2)*XPITCH+12];
            c0 = xq[(t+3)*4+0]; c1 = xq[(t+3)*4+1]; c2 = xq[(t+3)*4+2]; c3 = xst[(t+3)*XPITCH+12];

            // two independent 13-FMA chains (exact per-neuron order)
            float cura = b1r, curb = b1r;
#pragma unroll
            for (int c = 0; c < IN_SZ; ++c) {
                cura = fmaf(xa[c], w1r[c], cura);
                curb = fmaf(xc[c], w1r[c], curb);
            }

            // step t
            mem1 = fmaf(bt1, mem1, cura);
            const bool pa = mem1 > th1;
            const unsigned long long ma = __ballot(pa);
            mem1 = fmaf(pa ? -1.0f : 0.0f, th1, mem1);
            if (store_lane) mp[0] = ma;

            // step t+1
            mem1 = fmaf(bt1, mem1, curb);
            const bool pb = mem1 > th1;
            const unsigned long long mb = __ballot(pb);
            mem1 = fmaf(pb ? -1.0f : 0.0f, th1, mem1);
            if (store_lane) mp[2] = mb;

            mp += 4;
        }
        // tail step t = 344
        {
            const float xa[IN_SZ] = { a0.x,a0.y,a0.z,a0.w, a1.x,a1.y,a1.z,a1.w,
                                      a2.x,a2.y,a2.z,a2.w, a3 };
            float cura = b1r;
#pragma unroll
            for (int c = 0; c < IN_SZ; ++c) cura = fmaf(xa[c], w1r[c], cura);
            mem1 = fmaf(bt1, mem1, cura);
            const bool pa = mem1 > th1;
            const unsigned long long ma = __ballot(pa);
            if (store_lane) mp[0] = ma;
        }
    }
    __syncthreads();

    // ---------------- phase 2: cur2 bit-masked GEMM, all 8 waves ----------------
    // Wave-task = (o, 64-step stripe). half 0: tasks [0,30) (o 0..4);
    // half 1: tasks [30,54) (o 5..8). Lane = t within the stripe.
    {
        const int wave = tid >> 6;
        const int lane = tid & 63;
        const int tstart = half ? 30 : 0;
        const int tend   = half ? 54 : 30;
        for (int task = tstart + wave; task < tend; task += 8) {
            const int o  = task / 6;
            const int w  = task - o * 6;
            const int t  = w * 64 + lane;
            const int tc = (t < T_STEPS) ? t : (T_STEPS - 1);   // clamp load addr

            const uint4 mm = *(const uint4*)((const char*)msh + (size_t)tc * 16);

            const float* __restrict__ w2row = W2 + o * H_SZ;
            float acc = 0.0f;
#pragma unroll
            for (int h = 0; h < 32; ++h)
                acc = fmaf((float)((mm.x >> h) & 1u), w2row[h], acc);
#pragma unroll
            for (int h = 0; h < 32; ++h)
                acc = fmaf((float)((mm.y >> h) & 1u), w2row[32 + h], acc);
#pragma unroll
            for (int h = 0; h < 32; ++h)
                acc = fmaf((float)((mm.z >> h) & 1u), w2row[64 + h], acc);
#pragma unroll
            for (int h = 0; h < 32; ++h)
                acc = fmaf((float)((mm.w >> h) & 1u), w2row[96 + h], acc);

            c2s[o * CPAD + t] = acc + b2[o];
        }
    }
    __syncthreads();

    // ---------------- phase 3: mem2 scan, one lane per owned (b,o) row ----------------
    {
        const int nrows = half ? 4 : 5;
        if (tid < nrows) {
            const int o = (half ? 5 : 0) + tid;
            const float bt2 = fminf(fmaxf(beta2p[0], 0.0f), 1.0f);
            const float th2 = thr2p[0];
            const int lid = b * OUT_SZ + o;

            const float4* __restrict__ src = (const float4*)(c2s + o * CPAD);
            float* __restrict__ out_spk = out + lid;
            float* __restrict__ out_mem = out + (size_t)T_STEPS * NBO + lid;

            float mem2 = 0.0f;
            float4 f0 = src[0], f1 = src[1], f2 = src[2], f3 = src[3];

            // 88 groups of 4 steps; prefetch 4 groups (16 steps) ahead.
            for (int g = 0; g < 88; g += 4) {
                const float4 u0 = f0, u1 = f1, u2 = f2, u3 = f3;
                f0 = src[g + 4]; f1 = src[g + 5]; f2 = src[g + 6]; f3 = src[g + 7]; // <= src[91] < 96 ✓

                const float4 us[4] = { u0, u1, u2, u3 };
#pragma unroll
                for (int j = 0; j < 4; ++j) {
                    const float vv[4] = { us[j].x, us[j].y, us[j].z, us[j].w };
#pragma unroll
                    for (int k = 0; k < 4; ++k) {
                        const int tt = (g + j) * 4 + k;
                        mem2 = fmaf(bt2, mem2, vv[k]);
                        const float s2 = (mem2 > th2) ? 1.0f : 0.0f;
                        mem2 = fmaf(-s2, th2, mem2);
                        if (tt < T_STEPS) {
                            out_spk[(size_t)tt * NBO] = s2;
                            out_mem[(size_t)tt * NBO] = mem2;
                        }
                    }
                }
            }
        }
    }
}

extern "C" void kernel_launch(void* const* d_in, const int* in_sizes, int n_in,
                              void* d_out, int out_size, void* d_ws, size_t ws_size,
                              hipStream_t stream) {
    const float* x     = (const float*)d_in[0];
    const float* W1    = (const float*)d_in[1];
    const float* b1    = (const float*)d_in[2];
    const float* W2    = (const float*)d_in[3];
    const float* b2    = (const float*)d_in[4];
    const float* beta1 = (const float*)d_in[5];
    const float* thr1  = (const float*)d_in[6];
    const float* beta2 = (const float*)d_in[7];
    const float* thr2  = (const float*)d_in[8];
    float* out = (float*)d_out;
    (void)in_sizes; (void)n_in; (void)out_size; (void)d_ws; (void)ws_size;

    snn_fused<<<dim3(B_SZ * 2), dim3(512), 0, stream>>>(
        x, W1, b1, W2, b2, beta1, thr1, beta2, thr2, out);
}

// Round 2
// 103.730 us; speedup vs baseline: 1.2063x; 1.1940x over previous
//
#include <hip/hip_runtime.h>

#define T_STEPS 345
#define B_SZ    128
#define IN_SZ   13
#define H_SZ    128
#define OUT_SZ  9
#define CPAD    388                 // cur2 LDS row pitch (floats); 388*4=1552B, 16B-aligned
#define NBO     (B_SZ * OUT_SZ)    // 1152
#define CHUNK   92                  // layer-1 t-chunk (4 chunks: 92,92,92,69)
#define BUFR    100                 // cur1 buffer rows (CHUNK + prefetch overrun pad)

// v3: fused SNN with the serial scans stripped to their minimal recurrences.
// Phase 1a: cur1[t][h] GEMM computed by ALL waves into double-buffered LDS
//           (per-(t,h) 13-FMA order identical to the verified kernel — bit-exact).
// Phase 1b: mem1 scan (waves 0-1, lane=h) pipelined against 1a of the next chunk.
// Phase 2/3: cur2 bit-masked dot (exact h-order) stripe-pipelined with the mem2
//           scan (wave 7 scans stripe s-1 while waves 0-6 compute stripe s).
// Numerics: select-of-(mem-thr) is bit-identical to fmaf(+/-1, thr, mem).

__device__ __forceinline__ void emit_cur1(float* __restrict__ buf,
                                          const float* __restrict__ xst,
                                          const float (&w1r)[4][IN_SZ],
                                          const float (&b1r)[4],
                                          int T0, int L, int hq, int off, int stride)
{
    for (int tl = off; tl < L; tl += stride) {
        const int t = T0 + tl;
        const float4* xq = (const float4*)(xst + t * 16);
        const float4 x0 = xq[0], x1 = xq[1], x2 = xq[2];
        const float x12 = xst[t * 16 + 12];
        const float xa[IN_SZ] = { x0.x,x0.y,x0.z,x0.w, x1.x,x1.y,x1.z,x1.w,
                                  x2.x,x2.y,x2.z,x2.w, x12 };
        float* brow = buf + tl * H_SZ + hq;
#pragma unroll
        for (int k2 = 0; k2 < 4; ++k2) {
            float cur = b1r[k2];
#pragma unroll
            for (int c = 0; c < IN_SZ; ++c) cur = fmaf(xa[c], w1r[k2][c], cur);
            brow[k2 * 32] = cur;
        }
    }
}

__device__ __forceinline__ void scan1_step(float& mem1, float u, float bt1, float th1,
                                           unsigned long long* __restrict__ msh,
                                           int t, bool sl, int half)
{
    mem1 = fmaf(bt1, mem1, u);
    const bool p = mem1 > th1;
    const unsigned long long m = __ballot(p);
    const float ms = mem1 - th1;            // == fmaf(-1, th1, mem1) bitwise
    mem1 = p ? ms : mem1;
    if (sl) msh[t * 2 + half] = m;
}

__device__ __forceinline__ void scan1_chunk(const float* __restrict__ buf,
                                            unsigned long long* __restrict__ msh,
                                            int T0, int L, int h,
                                            float bt1, float th1, float& mem1)
{
    const float* cb = buf + h;              // column h, row stride 128 floats
    const bool sl = (h & 63) == 0;
    const int half = h >> 6;
    // 8-deep (2-group) rolling prefetch
    float a0 = cb[0*128], a1 = cb[1*128], a2 = cb[2*128], a3 = cb[3*128];
    float b0 = cb[4*128], b1v = cb[5*128], b2v = cb[6*128], b3 = cb[7*128];
    const int fullg = L >> 2;
    const int rem   = L & 3;
    for (int g = 0; g < fullg; ++g) {
        const float u0 = a0, u1 = a1, u2 = a2, u3 = a3;
        a0 = b0; a1 = b1v; a2 = b2v; a3 = b3;
        const float* nb = cb + (g + 2) * 4 * 128;   // rows <= 99 < BUFR
        b0 = nb[0]; b1v = nb[128]; b2v = nb[256]; b3 = nb[384];
        const int tb = T0 + g * 4;
        scan1_step(mem1, u0, bt1, th1, msh, tb + 0, sl, half);
        scan1_step(mem1, u1, bt1, th1, msh, tb + 1, sl, half);
        scan1_step(mem1, u2, bt1, th1, msh, tb + 2, sl, half);
        scan1_step(mem1, u3, bt1, th1, msh, tb + 3, sl, half);
    }
    const int tb = T0 + fullg * 4;
    if (rem > 0) scan1_step(mem1, a0, bt1, th1, msh, tb + 0, sl, half);
    if (rem > 1) scan1_step(mem1, a1, bt1, th1, msh, tb + 1, sl, half);
    if (rem > 2) scan1_step(mem1, a2, bt1, th1, msh, tb + 2, sl, half);
}

__global__ __launch_bounds__(512, 2)
void snn_fused(const float* __restrict__ x, const float* __restrict__ W1,
               const float* __restrict__ b1, const float* __restrict__ W2,
               const float* __restrict__ b2,
               const float* __restrict__ beta1p, const float* __restrict__ thr1p,
               const float* __restrict__ beta2p, const float* __restrict__ thr2p,
               float* __restrict__ out)
{
    const int b    = blockIdx.x >> 1;
    const int half = blockIdx.x & 1;
    const int tid  = threadIdx.x;
    const int wid  = tid >> 6;
    const int lane = tid & 63;

    __shared__ __align__(16) float xst[T_STEPS * 16];            // 22,080 B
    __shared__ __align__(16) float cur1s[2][BUFR * H_SZ];        // 102,400 B
    __shared__ __align__(16) unsigned long long msh[352 * 2];    //  5,632 B
    __shared__ __align__(16) float c2s[OUT_SZ * CPAD];           // 13,968 B

    // ---------------- phase 0: stage x[b] and W1^T into LDS ----------------
    const float* xb = x + (size_t)b * (IN_SZ * T_STEPS);
    for (int i = tid; i < IN_SZ * T_STEPS; i += 512) {
        const int c = i / T_STEPS;
        const int t = i - c * T_STEPS;
        xst[t * 16 + c] = xb[i];
    }
    float* W1t = c2s;   // c2s is free until phase 2; holds W1t[c*128 + h]
    for (int i = tid; i < IN_SZ * H_SZ; i += 512) {
        const int h = i / IN_SZ;
        const int c = i - IN_SZ * h;
        W1t[c * H_SZ + h] = W1[i];
    }
    __syncthreads();

    // ---------------- per-thread layer-1 weights (4 h-rows each) ----------------
    const int hq = tid & 31;
    float w1r[4][IN_SZ];
    float b1r[4];
#pragma unroll
    for (int k2 = 0; k2 < 4; ++k2) {
        b1r[k2] = b1[hq + 32 * k2];
#pragma unroll
        for (int c = 0; c < IN_SZ; ++c) w1r[k2][c] = W1t[c * H_SZ + hq + 32 * k2];
    }
    const float bt1 = fminf(fmaxf(beta1p[0], 0.0f), 1.0f);
    const float th1 = thr1p[0];

    // ---------------- phase 1: chunked cur1 GEMM pipelined with mem1 scan ----------------
    // chunk k: T0 = 92k, L = 92 (k<3) else 69
    emit_cur1(cur1s[0], xst, w1r, b1r, 0, CHUNK, hq, tid >> 5, 16);
    __syncthreads();

    float mem1 = 0.0f;
    for (int k = 0; k < 4; ++k) {
        if (tid < 128) {
            const int L = (k < 3) ? CHUNK : (T_STEPS - 3 * CHUNK);
            scan1_chunk(cur1s[k & 1], msh, k * CHUNK, L, tid, bt1, th1, mem1);
        } else if (k < 3) {
            const int kn = k + 1;
            const int L = (kn < 3) ? CHUNK : (T_STEPS - 3 * CHUNK);
            emit_cur1(cur1s[kn & 1], xst, w1r, b1r, kn * CHUNK, L, hq, (tid >> 5) - 4, 12);
        }
        __syncthreads();
    }

    // ---------------- phase 2/3: stripe-pipelined cur2 GEMM + mem2 scan ----------------
    const int obase  = half ? 5 : 0;
    const int ntasks = half ? 4 : 5;
    const float bt2 = fminf(fmaxf(beta2p[0], 0.0f), 1.0f);
    const float th2 = thr2p[0];

    float mem2 = 0.0f;
    const int o_sc = obase + lane;                       // scanner's output row (wave 7)
    float* out_spk = out + (size_t)b * OUT_SZ + o_sc;
    float* out_mem = out_spk + (size_t)T_STEPS * NBO;
    const float4* src4 = (const float4*)(c2s + lane * CPAD);

    for (int s = 0; s < 6; ++s) {
        if (wid < 7) {
            if (wid < ntasks) {
                const int o = obase + wid;
                const int t = s * 64 + lane;
                const int tc = (t < T_STEPS) ? t : (T_STEPS - 1);
                const uint4 mm = *(const uint4*)((const char*)msh + (size_t)tc * 16);
                const float* __restrict__ w2row = W2 + o * H_SZ;
                float acc = 0.0f;
#pragma unroll
                for (int h = 0; h < 32; ++h)
                    acc = fmaf((float)((mm.x >> h) & 1u), w2row[h], acc);
#pragma unroll
                for (int h = 0; h < 32; ++h)
                    acc = fmaf((float)((mm.y >> h) & 1u), w2row[32 + h], acc);
#pragma unroll
                for (int h = 0; h < 32; ++h)
                    acc = fmaf((float)((mm.z >> h) & 1u), w2row[64 + h], acc);
#pragma unroll
                for (int h = 0; h < 32; ++h)
                    acc = fmaf((float)((mm.w >> h) & 1u), w2row[96 + h], acc);
                c2s[wid * CPAD + t] = acc + b2[o];
            }
        } else if (s > 0 && lane < ntasks) {
            // scan stripe s-1 (guard-free: stripes 0..4 are fully in-range)
            const int sb = (s - 1) * 16;
            float4 fA = src4[sb], fB = src4[sb + 1];
#pragma unroll
            for (int i = 0; i < 16; ++i) {
                const float4 u = fA; fA = fB; fB = src4[sb + i + 2];
                const float vv[4] = { u.x, u.y, u.z, u.w };
#pragma unroll
                for (int kk = 0; kk < 4; ++kk) {
                    const int tt = (s - 1) * 64 + i * 4 + kk;
                    mem2 = fmaf(bt2, mem2, vv[kk]);
                    const bool p = mem2 > th2;
                    const float s2 = p ? 1.0f : 0.0f;
                    const float ms = mem2 - th2;     // == fmaf(-1, th2, mem2) bitwise
                    mem2 = p ? ms : mem2;
                    out_spk[(size_t)tt * NBO] = s2;
                    out_mem[(size_t)tt * NBO] = mem2;
                }
            }
        }
        __syncthreads();
    }

    // tail: scan stripe 5 (steps 320..344, guarded)
    if (wid == 7 && lane < ntasks) {
        const int sb = 5 * 16;
        float4 fA = src4[sb], fB = src4[sb + 1];
#pragma unroll
        for (int i = 0; i < 16; ++i) {
            const float4 u = fA; fA = fB; fB = src4[sb + i + 2];   // over-read in-bounds, discarded
            const float vv[4] = { u.x, u.y, u.z, u.w };
#pragma unroll
            for (int kk = 0; kk < 4; ++kk) {
                const int tt = 5 * 64 + i * 4 + kk;
                if (tt < T_STEPS) {
                    mem2 = fmaf(bt2, mem2, vv[kk]);
                    const bool p = mem2 > th2;
                    const float s2 = p ? 1.0f : 0.0f;
                    const float ms = mem2 - th2;
                    mem2 = p ? ms : mem2;
                    out_spk[(size_t)tt * NBO] = s2;
                    out_mem[(size_t)tt * NBO] = mem2;
                }
            }
        }
    }
}

extern "C" void kernel_launch(void* const* d_in, const int* in_sizes, int n_in,
                              void* d_out, int out_size, void* d_ws, size_t ws_size,
                              hipStream_t stream) {
    const float* x     = (const float*)d_in[0];
    const float* W1    = (const float*)d_in[1];
    const float* b1    = (const float*)d_in[2];
    const float* W2    = (const float*)d_in[3];
    const float* b2    = (const float*)d_in[4];
    const float* beta1 = (const float*)d_in[5];
    const float* thr1  = (const float*)d_in[6];
    const float* beta2 = (const float*)d_in[7];
    const float* thr2  = (const float*)d_in[8];
    float* out = (float*)d_out;
    (void)in_sizes; (void)n_in; (void)out_size; (void)d_ws; (void)ws_size;

    snn_fused<<<dim3(B_SZ * 2), dim3(512), 0, stream>>>(
        x, W1, b1, W2, b2, beta1, thr1, beta2, thr2, out);
}